// Round 3
// baseline (644.248 us; speedup 1.0000x reference)
//
#include <hip/hip_runtime.h>

#define NN 50000
#define NE 1600000
#define INDIM 256
#define HIDIM 128
#define OUTDIM 64

typedef unsigned int uint;
typedef unsigned short ushort;

__device__ __forceinline__ ushort f2bf(float f) {
    uint u = __float_as_uint(f);
    uint r = (u + 0x7FFFu + ((u >> 16) & 1u)) >> 16;   // RTNE
    return (ushort)r;
}
__device__ __forceinline__ float bf_lo(uint u) { return __uint_as_float(u << 16); }
__device__ __forceinline__ float bf_hi(uint u) { return __uint_as_float(u & 0xFFFF0000u); }

// ---------------- init / degree ----------------

__global__ void k_zero(int* __restrict__ cnt, int n) {
    int i = blockIdx.x * 256 + threadIdx.x;
    if (i < n) cnt[i] = 0;
}

__global__ void k_hist(const int* __restrict__ col, int* __restrict__ cnt, int e) {
    int i = blockIdx.x * 256 + threadIdx.x;
    if (i < e) atomicAdd(&cnt[col[i]], 1);
}

__global__ void k_dinv(const int* __restrict__ cnt, float* __restrict__ dinv, int n) {
    int i = blockIdx.x * 256 + threadIdx.x;
    if (i < n) dinv[i] = rsqrtf((float)(cnt[i] + 1));   // +1 self loop
}

// ---------------- exclusive scan (3 kernels) ----------------

__global__ void k_scan_part(const int* __restrict__ cnt, int* __restrict__ row_ptr,
                            int* __restrict__ blocksum, int n) {
    __shared__ int wsum[16];
    __shared__ int woff[16];
    int tid = threadIdx.x, lane = tid & 63, wid = tid >> 6;
    int i = blockIdx.x * 1024 + tid;
    int v = (i < n) ? cnt[i] : 0;
    int incl = v;
#pragma unroll
    for (int off = 1; off < 64; off <<= 1) {
        int t = __shfl_up(incl, off);
        if (lane >= off) incl += t;
    }
    if (lane == 63) wsum[wid] = incl;
    __syncthreads();
    if (wid == 0 && lane < 16) {
        int wv = wsum[lane];
        int wincl = wv;
#pragma unroll
        for (int off = 1; off < 16; off <<= 1) {
            int t = __shfl_up(wincl, off);
            if (lane >= off) wincl += t;
        }
        woff[lane] = wincl - wv;
    }
    __syncthreads();
    int excl = incl - v + woff[wid];
    if (i < n) row_ptr[i] = excl;
    if (tid == 1023) blocksum[blockIdx.x] = excl + v;
}

__global__ void k_scan_sums(const int* __restrict__ blocksum, int* __restrict__ blockoff,
                            int* __restrict__ row_ptr, int nchunks, int n) {
    int lane = threadIdx.x;
    int v = (lane < nchunks) ? blocksum[lane] : 0;
    int incl = v;
#pragma unroll
    for (int off = 1; off < 64; off <<= 1) {
        int t = __shfl_up(incl, off);
        if (lane >= off) incl += t;
    }
    blockoff[lane] = incl - v;
    if (lane == nchunks - 1) row_ptr[n] = incl;
}

__global__ void k_scan_add(int* __restrict__ row_ptr, const int* __restrict__ blockoff, int n) {
    int i = blockIdx.x * 1024 + threadIdx.x;
    if (i < n) row_ptr[i] += blockoff[blockIdx.x];
}

__global__ void k_fillinit(const int* __restrict__ row_ptr, int* __restrict__ fill, int n) {
    int i = blockIdx.x * 256 + threadIdx.x;
    if (i < n) fill[i] = row_ptr[i];
}

// ---------------- CSR placement (ushort src ids, no norm array) ----------------

__global__ void k_place(const int* __restrict__ row, const int* __restrict__ col,
                        int* __restrict__ fill, ushort* __restrict__ ssrc, int e) {
    int i = blockIdx.x * 256 + threadIdx.x;
    if (i >= e) return;
    int s = row[i], d = col[i];
    int pos = atomicAdd(&fill[d], 1);
    ssrc[pos] = (ushort)s;
}

// ---------------- GEMM1: x[n][256] @ W1[256][128] -> g1s sliced bf16 ----------------
// g1s layout: [8 slices][NN][16 feats], value = h1 * dinv[row]
// 128x128 tile, 256 threads (16x16), 8x8 micro-tile, KC=16.

__global__ void k_gemm1(const float* __restrict__ A, const float* __restrict__ W,
                        const float* __restrict__ dinv, ushort* __restrict__ g1s, int n) {
    __shared__ float xs[128][20];   // +4 pad: conflict-free, keeps 16B align
    __shared__ float ws[16][128];
    int tid = threadIdx.x;
    int tx = tid & 15, ty = tid >> 4;
    int row0 = blockIdx.x * 128;
    float acc[8][8] = {};

    for (int k0 = 0; k0 < INDIM; k0 += 16) {
#pragma unroll
        for (int it = 0; it < 2; it++) {            // stage x: 128 rows x 16
            int r = (tid >> 2) + it * 64;
            int kq = (tid & 3) << 2;
            int gr = row0 + r;
            float4 v = make_float4(0.f, 0.f, 0.f, 0.f);
            if (gr < n) v = *(const float4*)(A + (size_t)gr * INDIM + k0 + kq);
            *(float4*)&xs[r][kq] = v;
        }
#pragma unroll
        for (int it = 0; it < 2; it++) {            // stage W: 16 x 128
            int idx = tid + it * 256;               // float4 index
            int kk = idx >> 5, j = (idx & 31) << 2;
            *(float4*)&ws[kk][j] = *(const float4*)(W + (size_t)(k0 + kk) * HIDIM + j);
        }
        __syncthreads();
#pragma unroll
        for (int kk = 0; kk < 16; kk++) {
            float b[8];
            *(float4*)&b[0] = *(float4*)&ws[kk][tx * 8];
            *(float4*)&b[4] = *(float4*)&ws[kk][tx * 8 + 4];
#pragma unroll
            for (int i = 0; i < 8; i++) {
                float a = xs[ty + 16 * i][kk];
#pragma unroll
                for (int j = 0; j < 8; j++) acc[i][j] += a * b[j];
            }
        }
        __syncthreads();
    }
    int s  = tx >> 1;            // slice index (16 feats/slice)
    int jo = (tx & 1) * 8;       // offset within slice
#pragma unroll
    for (int i = 0; i < 8; i++) {
        int gr = row0 + ty + 16 * i;
        if (gr < n) {
            float dv = dinv[gr];
            ushort4 o0, o1;
            o0.x = f2bf(acc[i][0] * dv); o0.y = f2bf(acc[i][1] * dv);
            o0.z = f2bf(acc[i][2] * dv); o0.w = f2bf(acc[i][3] * dv);
            o1.x = f2bf(acc[i][4] * dv); o1.y = f2bf(acc[i][5] * dv);
            o1.z = f2bf(acc[i][6] * dv); o1.w = f2bf(acc[i][7] * dv);
            ushort* p = g1s + ((size_t)s * NN + gr) * 16 + jo;
            *(ushort4*)p = o0;
            *(ushort4*)(p + 4) = o1;
        }
    }
}

// ---------------- agg1: hr[s][d][16] = relu(dinv[d]*(sum g1[src] + g1[d]) + b1) ----
// block: 4 waves = 4 dsts; slice = blockIdx&7 (XCD-pinned). Wave: 8 edges x 8 lanes.

__global__ void k_agg1(const ushort* __restrict__ g1s, const float* __restrict__ dinv,
                       const int* __restrict__ row_ptr, const ushort* __restrict__ ssrc,
                       const float* __restrict__ b1, float* __restrict__ hr) {
    int wid = threadIdx.x >> 6, lane = threadIdx.x & 63;
    int s_slice = blockIdx.x & 7;
    int d = (blockIdx.x >> 3) * 4 + wid;
    int e_sub = lane >> 3;     // 0..7 edge subgroup
    int f2 = lane & 7;         // uint (2 feats) within 16-feat slice
    const ushort* gs = g1s + (size_t)s_slice * NN * 16;
    float ax = 0.f, ay = 0.f;
    int e0 = row_ptr[d], e1 = row_ptr[d + 1];
    for (int e = e0 + e_sub; e < e1; e += 8) {
        int src = ssrc[e];
        uint g = *(const uint*)(gs + (size_t)src * 16 + f2 * 2);
        ax += bf_lo(g);
        ay += bf_hi(g);
    }
    ax += __shfl_xor(ax, 8);  ay += __shfl_xor(ay, 8);
    ax += __shfl_xor(ax, 16); ay += __shfl_xor(ay, 16);
    ax += __shfl_xor(ax, 32); ay += __shfl_xor(ay, 32);
    if (e_sub == 0) {
        uint gd = *(const uint*)(gs + (size_t)d * 16 + f2 * 2);
        float dv = dinv[d];
        float rx = fmaxf((ax + bf_lo(gd)) * dv + b1[s_slice * 16 + f2 * 2], 0.f);
        float ry = fmaxf((ay + bf_hi(gd)) * dv + b1[s_slice * 16 + f2 * 2 + 1], 0.f);
        *(float2*)(hr + ((size_t)s_slice * NN + d) * 16 + f2 * 2) = make_float2(rx, ry);
    }
}

// ---------------- GEMM2: hr sliced [8][NN][16] @ W2[128][64] -> g2s [8][NN][8] bf16 --
// 256x64 tile, 256 threads (8x32), 8x8 micro-tile, KC=16.

__global__ void k_gemm2(const float* __restrict__ hr, const float* __restrict__ W,
                        const float* __restrict__ dinv, ushort* __restrict__ g2s, int n) {
    __shared__ float xs[256][20];
    __shared__ float ws[16][64];
    int tid = threadIdx.x;
    int tx = tid & 7, ty = tid >> 3;    // tx: col group (slice), ty: 0..31 row group
    int row0 = blockIdx.x * 256;
    float acc[8][8] = {};

    for (int k0 = 0; k0 < HIDIM; k0 += 16) {
        int s = k0 >> 4;                            // source slice of hr
#pragma unroll
        for (int it = 0; it < 4; it++) {            // stage A: 256 rows x 16
            int r = (tid >> 2) + it * 64;
            int kq = (tid & 3) << 2;
            int gr = row0 + r;
            float4 v = make_float4(0.f, 0.f, 0.f, 0.f);
            if (gr < n) v = *(const float4*)(hr + ((size_t)s * NN + gr) * 16 + kq);
            *(float4*)&xs[r][kq] = v;
        }
        {                                           // stage W: 16 x 64 = 256 float4
            int kk = tid >> 4, j = (tid & 15) << 2;
            *(float4*)&ws[kk][j] = *(const float4*)(W + (size_t)(k0 + kk) * OUTDIM + j);
        }
        __syncthreads();
#pragma unroll
        for (int kk = 0; kk < 16; kk++) {
            float b[8];
            *(float4*)&b[0] = *(float4*)&ws[kk][tx * 8];
            *(float4*)&b[4] = *(float4*)&ws[kk][tx * 8 + 4];
#pragma unroll
            for (int i = 0; i < 8; i++) {
                float a = xs[ty + 32 * i][kk];
#pragma unroll
                for (int j = 0; j < 8; j++) acc[i][j] += a * b[j];
            }
        }
        __syncthreads();
    }
    // cols tx*8..tx*8+7 == slice tx exactly (8 feats/slice)
#pragma unroll
    for (int i = 0; i < 8; i++) {
        int gr = row0 + ty + 32 * i;
        if (gr < n) {
            float dv = dinv[gr];
            ushort4 o0, o1;
            o0.x = f2bf(acc[i][0] * dv); o0.y = f2bf(acc[i][1] * dv);
            o0.z = f2bf(acc[i][2] * dv); o0.w = f2bf(acc[i][3] * dv);
            o1.x = f2bf(acc[i][4] * dv); o1.y = f2bf(acc[i][5] * dv);
            o1.z = f2bf(acc[i][6] * dv); o1.w = f2bf(acc[i][7] * dv);
            ushort* p = g2s + ((size_t)tx * NN + gr) * 8;
            *(ushort4*)p = o0;
            *(ushort4*)(p + 4) = o1;
        }
    }
}

// ---------------- agg2: out[d][64] = dinv[d]*(sum g2[src] + g2[d]) + b2 -------------
// slice = blockIdx&7 (8 feats). Wave: 16 edges x 4 lanes.

__global__ void k_agg2(const ushort* __restrict__ g2s, const float* __restrict__ dinv,
                       const int* __restrict__ row_ptr, const ushort* __restrict__ ssrc,
                       const float* __restrict__ b2, float* __restrict__ out) {
    int wid = threadIdx.x >> 6, lane = threadIdx.x & 63;
    int s_slice = blockIdx.x & 7;
    int d = (blockIdx.x >> 3) * 4 + wid;
    int e_sub = lane >> 2;     // 0..15
    int f2 = lane & 3;         // uint (2 feats) within 8-feat slice
    const ushort* gs = g2s + (size_t)s_slice * NN * 8;
    float ax = 0.f, ay = 0.f;
    int e0 = row_ptr[d], e1 = row_ptr[d + 1];
    for (int e = e0 + e_sub; e < e1; e += 16) {
        int src = ssrc[e];
        uint g = *(const uint*)(gs + (size_t)src * 8 + f2 * 2);
        ax += bf_lo(g);
        ay += bf_hi(g);
    }
    ax += __shfl_xor(ax, 4);  ay += __shfl_xor(ay, 4);
    ax += __shfl_xor(ax, 8);  ay += __shfl_xor(ay, 8);
    ax += __shfl_xor(ax, 16); ay += __shfl_xor(ay, 16);
    ax += __shfl_xor(ax, 32); ay += __shfl_xor(ay, 32);
    if (e_sub == 0) {
        uint gd = *(const uint*)(gs + (size_t)d * 8 + f2 * 2);
        float dv = dinv[d];
        float rx = (ax + bf_lo(gd)) * dv + b2[s_slice * 8 + f2 * 2];
        float ry = (ay + bf_hi(gd)) * dv + b2[s_slice * 8 + f2 * 2 + 1];
        *(float2*)(out + (size_t)d * OUTDIM + s_slice * 8 + f2 * 2) = make_float2(rx, ry);
    }
}

// ---------------- launch ----------------

extern "C" void kernel_launch(void* const* d_in, const int* in_sizes, int n_in,
                              void* d_out, int out_size, void* d_ws, size_t ws_size,
                              hipStream_t stream) {
    const float* x   = (const float*)d_in[0];
    const int*   ei  = (const int*)d_in[1];
    const float* W1  = (const float*)d_in[2];
    const float* b1  = (const float*)d_in[3];
    const float* W2  = (const float*)d_in[4];
    const float* b2  = (const float*)d_in[5];
    float* out = (float*)d_out;

    const int* row = ei;        // sources
    const int* col = ei + NE;   // destinations

    size_t off = 0;
    auto alloc = [&](size_t bytes) {
        void* p = (char*)d_ws + off;
        off += (bytes + 255) & ~(size_t)255;
        return p;
    };
    float*  dinv     = (float*) alloc((size_t)NN * 4);
    int*    cnt      = (int*)   alloc((size_t)NN * 4);
    int*    fill     = (int*)   alloc((size_t)NN * 4);
    int*    row_ptr  = (int*)   alloc((size_t)(NN + 1) * 4);
    int*    blocksum = (int*)   alloc(64 * 4);
    int*    blockoff = (int*)   alloc(64 * 4);
    ushort* ssrc     = (ushort*)alloc((size_t)NE * 2);
    ushort* g1s      = (ushort*)alloc((size_t)NN * HIDIM * 2);
    float*  hr       = (float*) alloc((size_t)NN * HIDIM * 4);
    ushort* g2s      = (ushort*)alloc((size_t)NN * OUTDIM * 2);

    const int nchunks = (NN + 1023) / 1024;  // 49

    k_zero<<<(NN + 255) / 256, 256, 0, stream>>>(cnt, NN);
    k_hist<<<(NE + 255) / 256, 256, 0, stream>>>(col, cnt, NE);
    k_dinv<<<(NN + 255) / 256, 256, 0, stream>>>(cnt, dinv, NN);

    k_scan_part<<<nchunks, 1024, 0, stream>>>(cnt, row_ptr, blocksum, NN);
    k_scan_sums<<<1, 64, 0, stream>>>(blocksum, blockoff, row_ptr, nchunks, NN);
    k_scan_add<<<nchunks, 1024, 0, stream>>>(row_ptr, blockoff, NN);
    k_fillinit<<<(NN + 255) / 256, 256, 0, stream>>>(row_ptr, fill, NN);

    k_place<<<(NE + 255) / 256, 256, 0, stream>>>(row, col, fill, ssrc, NE);

    k_gemm1<<<(NN + 127) / 128, 256, 0, stream>>>(x, W1, dinv, g1s, NN);
    k_agg1<<<(NN / 4) * 8, 256, 0, stream>>>(g1s, dinv, row_ptr, ssrc, b1, hr);
    k_gemm2<<<(NN + 255) / 256, 256, 0, stream>>>(hr, W2, dinv, g2s, NN);
    k_agg2<<<(NN / 4) * 8, 256, 0, stream>>>(g2s, dinv, row_ptr, ssrc, b2, out);
}

// Round 4
// 510.151 us; speedup vs baseline: 1.2629x; 1.2629x over previous
//
#include <hip/hip_runtime.h>

#define NN 50000
#define NE 1600000
#define INDIM 256
#define HIDIM 128
#define OUTDIM 64

typedef unsigned int uint;
typedef unsigned short ushort;

__device__ __forceinline__ ushort f2bf(float f) {
    uint u = __float_as_uint(f);
    uint r = (u + 0x7FFFu + ((u >> 16) & 1u)) >> 16;   // RTNE
    return (ushort)r;
}
__device__ __forceinline__ float bf_lo(uint u) { return __uint_as_float(u << 16); }
__device__ __forceinline__ float bf_hi(uint u) { return __uint_as_float(u & 0xFFFF0000u); }

// ---------------- init / degree ----------------

__global__ void k_zero(int* __restrict__ cnt, int n) {
    int i = blockIdx.x * 256 + threadIdx.x;
    if (i < n) cnt[i] = 0;
}

__global__ void k_hist(const int* __restrict__ col, int* __restrict__ cnt, int e) {
    int i = blockIdx.x * 256 + threadIdx.x;
    if (i < e) atomicAdd(&cnt[col[i]], 1);
}

__global__ void k_dinv(const int* __restrict__ cnt, float* __restrict__ dinv, int n) {
    int i = blockIdx.x * 256 + threadIdx.x;
    if (i < n) dinv[i] = rsqrtf((float)(cnt[i] + 1));   // +1 self loop
}

// ---------------- exclusive scan (3 kernels) ----------------

__global__ void k_scan_part(const int* __restrict__ cnt, int* __restrict__ row_ptr,
                            int* __restrict__ blocksum, int n) {
    __shared__ int wsum[16];
    __shared__ int woff[16];
    int tid = threadIdx.x, lane = tid & 63, wid = tid >> 6;
    int i = blockIdx.x * 1024 + tid;
    int v = (i < n) ? cnt[i] : 0;
    int incl = v;
#pragma unroll
    for (int off = 1; off < 64; off <<= 1) {
        int t = __shfl_up(incl, off);
        if (lane >= off) incl += t;
    }
    if (lane == 63) wsum[wid] = incl;
    __syncthreads();
    if (wid == 0 && lane < 16) {
        int wv = wsum[lane];
        int wincl = wv;
#pragma unroll
        for (int off = 1; off < 16; off <<= 1) {
            int t = __shfl_up(wincl, off);
            if (lane >= off) wincl += t;
        }
        woff[lane] = wincl - wv;
    }
    __syncthreads();
    int excl = incl - v + woff[wid];
    if (i < n) row_ptr[i] = excl;
    if (tid == 1023) blocksum[blockIdx.x] = excl + v;
}

__global__ void k_scan_sums(const int* __restrict__ blocksum, int* __restrict__ blockoff,
                            int* __restrict__ row_ptr, int nchunks, int n) {
    int lane = threadIdx.x;
    int v = (lane < nchunks) ? blocksum[lane] : 0;
    int incl = v;
#pragma unroll
    for (int off = 1; off < 64; off <<= 1) {
        int t = __shfl_up(incl, off);
        if (lane >= off) incl += t;
    }
    blockoff[lane] = incl - v;
    if (lane == nchunks - 1) row_ptr[n] = incl;
}

__global__ void k_scan_add(int* __restrict__ row_ptr, const int* __restrict__ blockoff, int n) {
    int i = blockIdx.x * 1024 + threadIdx.x;
    if (i < n) row_ptr[i] += blockoff[blockIdx.x];
}

__global__ void k_fillinit(const int* __restrict__ row_ptr, int* __restrict__ fill, int n) {
    int i = blockIdx.x * 256 + threadIdx.x;
    if (i < n) fill[i] = row_ptr[i];
}

// ---------------- CSR placement (ushort src ids) ----------------

__global__ void k_place(const int* __restrict__ row, const int* __restrict__ col,
                        int* __restrict__ fill, ushort* __restrict__ ssrc, int e) {
    int i = blockIdx.x * 256 + threadIdx.x;
    if (i >= e) return;
    int s = row[i], d = col[i];
    int pos = atomicAdd(&fill[d], 1);
    ssrc[pos] = (ushort)s;
}

// ---------------- GEMM1: x[n][256] @ W1[256][128] -> g1s [4][NN][32] bf16 ------------
// value = h1 * dinv[row]. 128x128 tile, 256 threads (16x16), 8x8 micro-tile, KC=16.

__global__ void k_gemm1(const float* __restrict__ A, const float* __restrict__ W,
                        const float* __restrict__ dinv, ushort* __restrict__ g1s, int n) {
    __shared__ float xs[128][20];   // +4 pad
    __shared__ float ws[16][128];
    int tid = threadIdx.x;
    int tx = tid & 15, ty = tid >> 4;
    int row0 = blockIdx.x * 128;
    float acc[8][8] = {};

    for (int k0 = 0; k0 < INDIM; k0 += 16) {
#pragma unroll
        for (int it = 0; it < 2; it++) {            // stage x: 128 rows x 16
            int r = (tid >> 2) + it * 64;
            int kq = (tid & 3) << 2;
            int gr = row0 + r;
            float4 v = make_float4(0.f, 0.f, 0.f, 0.f);
            if (gr < n) v = *(const float4*)(A + (size_t)gr * INDIM + k0 + kq);
            *(float4*)&xs[r][kq] = v;
        }
#pragma unroll
        for (int it = 0; it < 2; it++) {            // stage W: 16 x 128
            int idx = tid + it * 256;               // float4 index
            int kk = idx >> 5, j = (idx & 31) << 2;
            *(float4*)&ws[kk][j] = *(const float4*)(W + (size_t)(k0 + kk) * HIDIM + j);
        }
        __syncthreads();
#pragma unroll
        for (int kk = 0; kk < 16; kk++) {
            float b[8];
            *(float4*)&b[0] = *(float4*)&ws[kk][tx * 8];
            *(float4*)&b[4] = *(float4*)&ws[kk][tx * 8 + 4];
#pragma unroll
            for (int i = 0; i < 8; i++) {
                float a = xs[ty + 16 * i][kk];
#pragma unroll
                for (int j = 0; j < 8; j++) acc[i][j] += a * b[j];
            }
        }
        __syncthreads();
    }
    int s  = tx >> 2;            // 32-feat slice index
    int jo = (tx & 3) * 8;       // offset within slice
#pragma unroll
    for (int i = 0; i < 8; i++) {
        int gr = row0 + ty + 16 * i;
        if (gr < n) {
            float dv = dinv[gr];
            ushort4 o0, o1;
            o0.x = f2bf(acc[i][0] * dv); o0.y = f2bf(acc[i][1] * dv);
            o0.z = f2bf(acc[i][2] * dv); o0.w = f2bf(acc[i][3] * dv);
            o1.x = f2bf(acc[i][4] * dv); o1.y = f2bf(acc[i][5] * dv);
            o1.z = f2bf(acc[i][6] * dv); o1.w = f2bf(acc[i][7] * dv);
            ushort* p = g1s + ((size_t)s * NN + gr) * 32 + jo;
            *(ushort4*)p = o0;
            *(ushort4*)(p + 4) = o1;
        }
    }
}

// ---------------- agg1: hr[s][d][32] = relu(dinv[d]*(sum g1[src] + g1[d]) + b1) -----
// 4 slices x 32 feats. Wave: 8 dst-groups x 8 lanes, lane owns 4 feats (uint2 gather).
// No shuffles; each group walks its dst's edges serially. slice = blk&3 (XCD-pinned).

__global__ void k_agg1(const ushort* __restrict__ g1s, const float* __restrict__ dinv,
                       const int* __restrict__ row_ptr, const ushort* __restrict__ ssrc,
                       const float* __restrict__ b1, float* __restrict__ hr) {
    int slice = blockIdx.x & 3;
    int dbase = (blockIdx.x >> 2) * 32;
    int wid = threadIdx.x >> 6, lane = threadIdx.x & 63;
    int grp = lane >> 3, fl = lane & 7;
    int d = dbase + wid * 8 + grp;
    if (d >= NN) return;
    const ushort* gs = g1s + (size_t)slice * NN * 32 + fl * 4;
    float a0 = 0.f, a1 = 0.f, a2 = 0.f, a3 = 0.f;
    int e0 = row_ptr[d], e1 = row_ptr[d + 1];
    int e = e0;
    for (; e + 1 < e1; e += 2) {
        int s0 = ssrc[e], s1 = ssrc[e + 1];
        uint2 u = *(const uint2*)(gs + (size_t)s0 * 32);
        uint2 v = *(const uint2*)(gs + (size_t)s1 * 32);
        a0 += bf_lo(u.x); a1 += bf_hi(u.x); a2 += bf_lo(u.y); a3 += bf_hi(u.y);
        a0 += bf_lo(v.x); a1 += bf_hi(v.x); a2 += bf_lo(v.y); a3 += bf_hi(v.y);
    }
    if (e < e1) {
        int s0 = ssrc[e];
        uint2 u = *(const uint2*)(gs + (size_t)s0 * 32);
        a0 += bf_lo(u.x); a1 += bf_hi(u.x); a2 += bf_lo(u.y); a3 += bf_hi(u.y);
    }
    uint2 ud = *(const uint2*)(gs + (size_t)d * 32);
    a0 += bf_lo(ud.x); a1 += bf_hi(ud.x); a2 += bf_lo(ud.y); a3 += bf_hi(ud.y);
    float dv = dinv[d];
    float4 bb = *(const float4*)(b1 + slice * 32 + fl * 4);
    float4 r;
    r.x = fmaxf(a0 * dv + bb.x, 0.f);
    r.y = fmaxf(a1 * dv + bb.y, 0.f);
    r.z = fmaxf(a2 * dv + bb.z, 0.f);
    r.w = fmaxf(a3 * dv + bb.w, 0.f);
    *(float4*)(hr + ((size_t)slice * NN + d) * 32 + fl * 4) = r;
}

// ---------------- GEMM2: hr [4][NN][32] @ W2[128][64] -> g2s [2][NN][32] bf16 --------
// 256x64 tile, 256 threads (8x32), 8x8 micro-tile, KC=16.

__global__ void k_gemm2(const float* __restrict__ hr, const float* __restrict__ W,
                        const float* __restrict__ dinv, ushort* __restrict__ g2s, int n) {
    __shared__ float xs[256][20];
    __shared__ float ws[16][64];
    int tid = threadIdx.x;
    int tx = tid & 7, ty = tid >> 3;
    int row0 = blockIdx.x * 256;
    float acc[8][8] = {};

    for (int k0 = 0; k0 < HIDIM; k0 += 16) {
        int hs = k0 >> 5;                           // hr slice
        int ko = k0 & 31;                           // offset in slice
#pragma unroll
        for (int it = 0; it < 4; it++) {            // stage A: 256 rows x 16
            int r = (tid >> 2) + it * 64;
            int kq = (tid & 3) << 2;
            int gr = row0 + r;
            float4 v = make_float4(0.f, 0.f, 0.f, 0.f);
            if (gr < n) v = *(const float4*)(hr + ((size_t)hs * NN + gr) * 32 + ko + kq);
            *(float4*)&xs[r][kq] = v;
        }
        {                                           // stage W: 16 x 64 = 256 float4
            int kk = tid >> 4, j = (tid & 15) << 2;
            *(float4*)&ws[kk][j] = *(const float4*)(W + (size_t)(k0 + kk) * OUTDIM + j);
        }
        __syncthreads();
#pragma unroll
        for (int kk = 0; kk < 16; kk++) {
            float b[8];
            *(float4*)&b[0] = *(float4*)&ws[kk][tx * 8];
            *(float4*)&b[4] = *(float4*)&ws[kk][tx * 8 + 4];
#pragma unroll
            for (int i = 0; i < 8; i++) {
                float a = xs[ty + 32 * i][kk];
#pragma unroll
                for (int j = 0; j < 8; j++) acc[i][j] += a * b[j];
            }
        }
        __syncthreads();
    }
    int s2 = tx >> 2;            // 32-feat slice
    int jo = (tx & 3) * 8;
#pragma unroll
    for (int i = 0; i < 8; i++) {
        int gr = row0 + ty + 32 * i;
        if (gr < n) {
            float dv = dinv[gr];
            ushort4 o0, o1;
            o0.x = f2bf(acc[i][0] * dv); o0.y = f2bf(acc[i][1] * dv);
            o0.z = f2bf(acc[i][2] * dv); o0.w = f2bf(acc[i][3] * dv);
            o1.x = f2bf(acc[i][4] * dv); o1.y = f2bf(acc[i][5] * dv);
            o1.z = f2bf(acc[i][6] * dv); o1.w = f2bf(acc[i][7] * dv);
            ushort* p = g2s + ((size_t)s2 * NN + gr) * 32 + jo;
            *(ushort4*)p = o0;
            *(ushort4*)(p + 4) = o1;
        }
    }
}

// ---------------- agg2: out[d][64] = dinv[d]*(sum g2[src] + g2[d]) + b2 --------------
// 2 slices x 32 feats, same wave layout as agg1, dense f32 output.

__global__ void k_agg2(const ushort* __restrict__ g2s, const float* __restrict__ dinv,
                       const int* __restrict__ row_ptr, const ushort* __restrict__ ssrc,
                       const float* __restrict__ b2, float* __restrict__ out) {
    int slice = blockIdx.x & 1;
    int dbase = (blockIdx.x >> 1) * 32;
    int wid = threadIdx.x >> 6, lane = threadIdx.x & 63;
    int grp = lane >> 3, fl = lane & 7;
    int d = dbase + wid * 8 + grp;
    if (d >= NN) return;
    const ushort* gs = g2s + (size_t)slice * NN * 32 + fl * 4;
    float a0 = 0.f, a1 = 0.f, a2 = 0.f, a3 = 0.f;
    int e0 = row_ptr[d], e1 = row_ptr[d + 1];
    int e = e0;
    for (; e + 1 < e1; e += 2) {
        int s0 = ssrc[e], s1 = ssrc[e + 1];
        uint2 u = *(const uint2*)(gs + (size_t)s0 * 32);
        uint2 v = *(const uint2*)(gs + (size_t)s1 * 32);
        a0 += bf_lo(u.x); a1 += bf_hi(u.x); a2 += bf_lo(u.y); a3 += bf_hi(u.y);
        a0 += bf_lo(v.x); a1 += bf_hi(v.x); a2 += bf_lo(v.y); a3 += bf_hi(v.y);
    }
    if (e < e1) {
        int s0 = ssrc[e];
        uint2 u = *(const uint2*)(gs + (size_t)s0 * 32);
        a0 += bf_lo(u.x); a1 += bf_hi(u.x); a2 += bf_lo(u.y); a3 += bf_hi(u.y);
    }
    uint2 ud = *(const uint2*)(gs + (size_t)d * 32);
    a0 += bf_lo(ud.x); a1 += bf_hi(ud.x); a2 += bf_lo(ud.y); a3 += bf_hi(ud.y);
    float dv = dinv[d];
    float4 bb = *(const float4*)(b2 + slice * 32 + fl * 4);
    float4 r;
    r.x = a0 * dv + bb.x;
    r.y = a1 * dv + bb.y;
    r.z = a2 * dv + bb.z;
    r.w = a3 * dv + bb.w;
    *(float4*)(out + (size_t)d * OUTDIM + slice * 32 + fl * 4) = r;
}

// ---------------- launch ----------------

extern "C" void kernel_launch(void* const* d_in, const int* in_sizes, int n_in,
                              void* d_out, int out_size, void* d_ws, size_t ws_size,
                              hipStream_t stream) {
    const float* x   = (const float*)d_in[0];
    const int*   ei  = (const int*)d_in[1];
    const float* W1  = (const float*)d_in[2];
    const float* b1  = (const float*)d_in[3];
    const float* W2  = (const float*)d_in[4];
    const float* b2  = (const float*)d_in[5];
    float* out = (float*)d_out;

    const int* row = ei;        // sources
    const int* col = ei + NE;   // destinations

    size_t off = 0;
    auto alloc = [&](size_t bytes) {
        void* p = (char*)d_ws + off;
        off += (bytes + 255) & ~(size_t)255;
        return p;
    };
    float*  dinv     = (float*) alloc((size_t)NN * 4);
    int*    cnt      = (int*)   alloc((size_t)NN * 4);
    int*    fill     = (int*)   alloc((size_t)NN * 4);
    int*    row_ptr  = (int*)   alloc((size_t)(NN + 1) * 4);
    int*    blocksum = (int*)   alloc(64 * 4);
    int*    blockoff = (int*)   alloc(64 * 4);
    ushort* ssrc     = (ushort*)alloc((size_t)NE * 2);
    ushort* g1s      = (ushort*)alloc((size_t)NN * HIDIM * 2);
    float*  hr       = (float*) alloc((size_t)NN * HIDIM * 4);
    ushort* g2s      = (ushort*)alloc((size_t)NN * OUTDIM * 2);

    const int nchunks = (NN + 1023) / 1024;  // 49
    const int nb32 = (NN + 31) / 32;         // 1563

    k_zero<<<(NN + 255) / 256, 256, 0, stream>>>(cnt, NN);
    k_hist<<<(NE + 255) / 256, 256, 0, stream>>>(col, cnt, NE);
    k_dinv<<<(NN + 255) / 256, 256, 0, stream>>>(cnt, dinv, NN);

    k_scan_part<<<nchunks, 1024, 0, stream>>>(cnt, row_ptr, blocksum, NN);
    k_scan_sums<<<1, 64, 0, stream>>>(blocksum, blockoff, row_ptr, nchunks, NN);
    k_scan_add<<<nchunks, 1024, 0, stream>>>(row_ptr, blockoff, NN);
    k_fillinit<<<(NN + 255) / 256, 256, 0, stream>>>(row_ptr, fill, NN);

    k_place<<<(NE + 255) / 256, 256, 0, stream>>>(row, col, fill, ssrc, NE);

    k_gemm1<<<(NN + 127) / 128, 256, 0, stream>>>(x, W1, dinv, g1s, NN);
    k_agg1<<<nb32 * 4, 256, 0, stream>>>(g1s, dinv, row_ptr, ssrc, b1, hr);
    k_gemm2<<<(NN + 255) / 256, 256, 0, stream>>>(hr, W2, dinv, g2s, NN);
    k_agg2<<<nb32 * 2, 256, 0, stream>>>(g2s, dinv, row_ptr, ssrc, b2, out);
}

// Round 5
// 456.391 us; speedup vs baseline: 1.4116x; 1.1178x over previous
//
#include <hip/hip_runtime.h>

#define NN 50000
#define NE 1600000
#define INDIM 256
#define HIDIM 128
#define OUTDIM 64

#define NRANGE 8
#define RSPAN 6250            // NN / NRANGE
#define PLACE_EPT 16
#define PLACE_CHUNK (256 * PLACE_EPT)

typedef unsigned int uint;
typedef unsigned short ushort;

__device__ __forceinline__ ushort f2bf(float f) {
    uint u = __float_as_uint(f);
    uint r = (u + 0x7FFFu + ((u >> 16) & 1u)) >> 16;   // RTNE
    return (ushort)r;
}
__device__ __forceinline__ float bf_lo(uint u) { return __uint_as_float(u << 16); }
__device__ __forceinline__ float bf_hi(uint u) { return __uint_as_float(u & 0xFFFF0000u); }

// ---------------- init / degree ----------------

__global__ void k_zero(int* __restrict__ cnt, int n) {
    int i = blockIdx.x * 256 + threadIdx.x;
    if (i < n) cnt[i] = 0;
}

__global__ void k_hist(const int* __restrict__ col, int* __restrict__ cnt, int e) {
    int i = blockIdx.x * 256 + threadIdx.x;
    if (i < e) atomicAdd(&cnt[col[i]], 1);
}

__global__ void k_dinv(const int* __restrict__ cnt, float* __restrict__ dinv, int n) {
    int i = blockIdx.x * 256 + threadIdx.x;
    if (i < n) dinv[i] = rsqrtf((float)(cnt[i] + 1));   // +1 self loop
}

// ---------------- exclusive scan (3 kernels) ----------------

__global__ void k_scan_part(const int* __restrict__ cnt, int* __restrict__ row_ptr,
                            int* __restrict__ blocksum, int n) {
    __shared__ int wsum[16];
    __shared__ int woff[16];
    int tid = threadIdx.x, lane = tid & 63, wid = tid >> 6;
    int i = blockIdx.x * 1024 + tid;
    int v = (i < n) ? cnt[i] : 0;
    int incl = v;
#pragma unroll
    for (int off = 1; off < 64; off <<= 1) {
        int t = __shfl_up(incl, off);
        if (lane >= off) incl += t;
    }
    if (lane == 63) wsum[wid] = incl;
    __syncthreads();
    if (wid == 0 && lane < 16) {
        int wv = wsum[lane];
        int wincl = wv;
#pragma unroll
        for (int off = 1; off < 16; off <<= 1) {
            int t = __shfl_up(wincl, off);
            if (lane >= off) wincl += t;
        }
        woff[lane] = wincl - wv;
    }
    __syncthreads();
    int excl = incl - v + woff[wid];
    if (i < n) row_ptr[i] = excl;
    if (tid == 1023) blocksum[blockIdx.x] = excl + v;
}

__global__ void k_scan_sums(const int* __restrict__ blocksum, int* __restrict__ blockoff,
                            int* __restrict__ row_ptr, int nchunks, int n) {
    int lane = threadIdx.x;
    int v = (lane < nchunks) ? blocksum[lane] : 0;
    int incl = v;
#pragma unroll
    for (int off = 1; off < 64; off <<= 1) {
        int t = __shfl_up(incl, off);
        if (lane >= off) incl += t;
    }
    blockoff[lane] = incl - v;
    if (lane == nchunks - 1) row_ptr[n] = incl;
}

__global__ void k_scan_add(int* __restrict__ row_ptr, const int* __restrict__ blockoff, int n) {
    int i = blockIdx.x * 1024 + threadIdx.x;
    if (i < n) row_ptr[i] += blockoff[blockIdx.x];
}

__global__ void k_fillinit(const int* __restrict__ row_ptr, int* __restrict__ fill, int n) {
    int i = blockIdx.x * 256 + threadIdx.x;
    if (i < n) fill[i] = row_ptr[i];
}

// ---------------- CSR placement: XCD-local dst-range filtered scatter ----------------
// blockIdx&7 = dst range (6250 nodes, ~400KB of ssrc -> one XCD's L2).
// Each block scans a 4096-edge chunk, scatters only its range's edges.

__global__ void k_place(const int* __restrict__ row, const int* __restrict__ col,
                        int* __restrict__ fill, ushort* __restrict__ ssrc, int e) {
    int r = blockIdx.x & (NRANGE - 1);
    int chunk = blockIdx.x >> 3;
    int base = chunk * PLACE_CHUNK + threadIdx.x;
    int lo = r * RSPAN, hi = lo + RSPAN;
#pragma unroll
    for (int k = 0; k < PLACE_EPT; k++) {
        int i = base + k * 256;
        if (i < e) {
            int d = col[i];
            if (d >= lo && d < hi) {
                int pos = atomicAdd(&fill[d], 1);
                ssrc[pos] = (ushort)row[i];
            }
        }
    }
}

// ---------------- GEMM1: x[n][256] @ W1[256][128] -> g1s [4][NN][32] bf16 ------------
// value = h1 * dinv[row]. 128x128 tile, 256 threads (16x16), 8x8 micro-tile, KC=16.

__global__ void k_gemm1(const float* __restrict__ A, const float* __restrict__ W,
                        const float* __restrict__ dinv, ushort* __restrict__ g1s, int n) {
    __shared__ float xs[128][20];   // +4 pad
    __shared__ float ws[16][128];
    int tid = threadIdx.x;
    int tx = tid & 15, ty = tid >> 4;
    int row0 = blockIdx.x * 128;
    float acc[8][8] = {};

    for (int k0 = 0; k0 < INDIM; k0 += 16) {
#pragma unroll
        for (int it = 0; it < 2; it++) {            // stage x: 128 rows x 16
            int r = (tid >> 2) + it * 64;
            int kq = (tid & 3) << 2;
            int gr = row0 + r;
            float4 v = make_float4(0.f, 0.f, 0.f, 0.f);
            if (gr < n) v = *(const float4*)(A + (size_t)gr * INDIM + k0 + kq);
            *(float4*)&xs[r][kq] = v;
        }
#pragma unroll
        for (int it = 0; it < 2; it++) {            // stage W: 16 x 128
            int idx = tid + it * 256;               // float4 index
            int kk = idx >> 5, j = (idx & 31) << 2;
            *(float4*)&ws[kk][j] = *(const float4*)(W + (size_t)(k0 + kk) * HIDIM + j);
        }
        __syncthreads();
#pragma unroll
        for (int kk = 0; kk < 16; kk++) {
            float b[8];
            *(float4*)&b[0] = *(float4*)&ws[kk][tx * 8];
            *(float4*)&b[4] = *(float4*)&ws[kk][tx * 8 + 4];
#pragma unroll
            for (int i = 0; i < 8; i++) {
                float a = xs[ty + 16 * i][kk];
#pragma unroll
                for (int j = 0; j < 8; j++) acc[i][j] += a * b[j];
            }
        }
        __syncthreads();
    }
    int s  = tx >> 2;            // 32-feat slice index
    int jo = (tx & 3) * 8;       // offset within slice
#pragma unroll
    for (int i = 0; i < 8; i++) {
        int gr = row0 + ty + 16 * i;
        if (gr < n) {
            float dv = dinv[gr];
            ushort4 o0, o1;
            o0.x = f2bf(acc[i][0] * dv); o0.y = f2bf(acc[i][1] * dv);
            o0.z = f2bf(acc[i][2] * dv); o0.w = f2bf(acc[i][3] * dv);
            o1.x = f2bf(acc[i][4] * dv); o1.y = f2bf(acc[i][5] * dv);
            o1.z = f2bf(acc[i][6] * dv); o1.w = f2bf(acc[i][7] * dv);
            ushort* p = g1s + ((size_t)s * NN + gr) * 32 + jo;
            *(ushort4*)p = o0;
            *(ushort4*)(p + 4) = o1;
        }
    }
}

// ---------------- agg1: hr[s][d][32] = relu(dinv[d]*(sum g1[src] + g1[d]) + b1) -----
// 4 slices x 32 feats. Wave: 8 dst-groups x 8 lanes, lane owns 4 feats (uint2 gather).

__global__ void k_agg1(const ushort* __restrict__ g1s, const float* __restrict__ dinv,
                       const int* __restrict__ row_ptr, const ushort* __restrict__ ssrc,
                       const float* __restrict__ b1, float* __restrict__ hr) {
    int slice = blockIdx.x & 3;
    int dbase = (blockIdx.x >> 2) * 32;
    int wid = threadIdx.x >> 6, lane = threadIdx.x & 63;
    int grp = lane >> 3, fl = lane & 7;
    int d = dbase + wid * 8 + grp;
    if (d >= NN) return;
    const ushort* gs = g1s + (size_t)slice * NN * 32 + fl * 4;
    float a0 = 0.f, a1 = 0.f, a2 = 0.f, a3 = 0.f;
    int e0 = row_ptr[d], e1 = row_ptr[d + 1];
    int e = e0;
    for (; e + 1 < e1; e += 2) {
        int s0 = ssrc[e], s1 = ssrc[e + 1];
        uint2 u = *(const uint2*)(gs + (size_t)s0 * 32);
        uint2 v = *(const uint2*)(gs + (size_t)s1 * 32);
        a0 += bf_lo(u.x); a1 += bf_hi(u.x); a2 += bf_lo(u.y); a3 += bf_hi(u.y);
        a0 += bf_lo(v.x); a1 += bf_hi(v.x); a2 += bf_lo(v.y); a3 += bf_hi(v.y);
    }
    if (e < e1) {
        int s0 = ssrc[e];
        uint2 u = *(const uint2*)(gs + (size_t)s0 * 32);
        a0 += bf_lo(u.x); a1 += bf_hi(u.x); a2 += bf_lo(u.y); a3 += bf_hi(u.y);
    }
    uint2 ud = *(const uint2*)(gs + (size_t)d * 32);
    a0 += bf_lo(ud.x); a1 += bf_hi(ud.x); a2 += bf_lo(ud.y); a3 += bf_hi(ud.y);
    float dv = dinv[d];
    float4 bb = *(const float4*)(b1 + slice * 32 + fl * 4);
    float4 r;
    r.x = fmaxf(a0 * dv + bb.x, 0.f);
    r.y = fmaxf(a1 * dv + bb.y, 0.f);
    r.z = fmaxf(a2 * dv + bb.z, 0.f);
    r.w = fmaxf(a3 * dv + bb.w, 0.f);
    *(float4*)(hr + ((size_t)slice * NN + d) * 32 + fl * 4) = r;
}

// ---------------- GEMM2: hr [4][NN][32] @ W2[128][64] -> g2s [2][NN][32] bf16 --------
// 256x64 tile, 256 threads (8x32), 8x8 micro-tile, KC=16.

__global__ void k_gemm2(const float* __restrict__ hr, const float* __restrict__ W,
                        const float* __restrict__ dinv, ushort* __restrict__ g2s, int n) {
    __shared__ float xs[256][20];
    __shared__ float ws[16][64];
    int tid = threadIdx.x;
    int tx = tid & 7, ty = tid >> 3;
    int row0 = blockIdx.x * 256;
    float acc[8][8] = {};

    for (int k0 = 0; k0 < HIDIM; k0 += 16) {
        int hs = k0 >> 5;                           // hr slice
        int ko = k0 & 31;                           // offset in slice
#pragma unroll
        for (int it = 0; it < 4; it++) {            // stage A: 256 rows x 16
            int r = (tid >> 2) + it * 64;
            int kq = (tid & 3) << 2;
            int gr = row0 + r;
            float4 v = make_float4(0.f, 0.f, 0.f, 0.f);
            if (gr < n) v = *(const float4*)(hr + ((size_t)hs * NN + gr) * 32 + ko + kq);
            *(float4*)&xs[r][kq] = v;
        }
        {                                           // stage W: 16 x 64 = 256 float4
            int kk = tid >> 4, j = (tid & 15) << 2;
            *(float4*)&ws[kk][j] = *(const float4*)(W + (size_t)(k0 + kk) * OUTDIM + j);
        }
        __syncthreads();
#pragma unroll
        for (int kk = 0; kk < 16; kk++) {
            float b[8];
            *(float4*)&b[0] = *(float4*)&ws[kk][tx * 8];
            *(float4*)&b[4] = *(float4*)&ws[kk][tx * 8 + 4];
#pragma unroll
            for (int i = 0; i < 8; i++) {
                float a = xs[ty + 32 * i][kk];
#pragma unroll
                for (int j = 0; j < 8; j++) acc[i][j] += a * b[j];
            }
        }
        __syncthreads();
    }
    int s2 = tx >> 2;            // 32-feat slice
    int jo = (tx & 3) * 8;
#pragma unroll
    for (int i = 0; i < 8; i++) {
        int gr = row0 + ty + 32 * i;
        if (gr < n) {
            float dv = dinv[gr];
            ushort4 o0, o1;
            o0.x = f2bf(acc[i][0] * dv); o0.y = f2bf(acc[i][1] * dv);
            o0.z = f2bf(acc[i][2] * dv); o0.w = f2bf(acc[i][3] * dv);
            o1.x = f2bf(acc[i][4] * dv); o1.y = f2bf(acc[i][5] * dv);
            o1.z = f2bf(acc[i][6] * dv); o1.w = f2bf(acc[i][7] * dv);
            ushort* p = g2s + ((size_t)s2 * NN + gr) * 32 + jo;
            *(ushort4*)p = o0;
            *(ushort4*)(p + 4) = o1;
        }
    }
}

// ---------------- agg2: out[d][64] = dinv[d]*(sum g2[src] + g2[d]) + b2 --------------

__global__ void k_agg2(const ushort* __restrict__ g2s, const float* __restrict__ dinv,
                       const int* __restrict__ row_ptr, const ushort* __restrict__ ssrc,
                       const float* __restrict__ b2, float* __restrict__ out) {
    int slice = blockIdx.x & 1;
    int dbase = (blockIdx.x >> 1) * 32;
    int wid = threadIdx.x >> 6, lane = threadIdx.x & 63;
    int grp = lane >> 3, fl = lane & 7;
    int d = dbase + wid * 8 + grp;
    if (d >= NN) return;
    const ushort* gs = g2s + (size_t)slice * NN * 32 + fl * 4;
    float a0 = 0.f, a1 = 0.f, a2 = 0.f, a3 = 0.f;
    int e0 = row_ptr[d], e1 = row_ptr[d + 1];
    int e = e0;
    for (; e + 1 < e1; e += 2) {
        int s0 = ssrc[e], s1 = ssrc[e + 1];
        uint2 u = *(const uint2*)(gs + (size_t)s0 * 32);
        uint2 v = *(const uint2*)(gs + (size_t)s1 * 32);
        a0 += bf_lo(u.x); a1 += bf_hi(u.x); a2 += bf_lo(u.y); a3 += bf_hi(u.y);
        a0 += bf_lo(v.x); a1 += bf_hi(v.x); a2 += bf_lo(v.y); a3 += bf_hi(v.y);
    }
    if (e < e1) {
        int s0 = ssrc[e];
        uint2 u = *(const uint2*)(gs + (size_t)s0 * 32);
        a0 += bf_lo(u.x); a1 += bf_hi(u.x); a2 += bf_lo(u.y); a3 += bf_hi(u.y);
    }
    uint2 ud = *(const uint2*)(gs + (size_t)d * 32);
    a0 += bf_lo(ud.x); a1 += bf_hi(ud.x); a2 += bf_lo(ud.y); a3 += bf_hi(ud.y);
    float dv = dinv[d];
    float4 bb = *(const float4*)(b2 + slice * 32 + fl * 4);
    float4 r;
    r.x = a0 * dv + bb.x;
    r.y = a1 * dv + bb.y;
    r.z = a2 * dv + bb.z;
    r.w = a3 * dv + bb.w;
    *(float4*)(out + (size_t)d * OUTDIM + slice * 32 + fl * 4) = r;
}

// ---------------- launch ----------------

extern "C" void kernel_launch(void* const* d_in, const int* in_sizes, int n_in,
                              void* d_out, int out_size, void* d_ws, size_t ws_size,
                              hipStream_t stream) {
    const float* x   = (const float*)d_in[0];
    const int*   ei  = (const int*)d_in[1];
    const float* W1  = (const float*)d_in[2];
    const float* b1  = (const float*)d_in[3];
    const float* W2  = (const float*)d_in[4];
    const float* b2  = (const float*)d_in[5];
    float* out = (float*)d_out;

    const int* row = ei;        // sources
    const int* col = ei + NE;   // destinations

    size_t off = 0;
    auto alloc = [&](size_t bytes) {
        void* p = (char*)d_ws + off;
        off += (bytes + 255) & ~(size_t)255;
        return p;
    };
    float*  dinv     = (float*) alloc((size_t)NN * 4);
    int*    cnt      = (int*)   alloc((size_t)NN * 4);
    int*    fill     = (int*)   alloc((size_t)NN * 4);
    int*    row_ptr  = (int*)   alloc((size_t)(NN + 1) * 4);
    int*    blocksum = (int*)   alloc(64 * 4);
    int*    blockoff = (int*)   alloc(64 * 4);
    ushort* ssrc     = (ushort*)alloc((size_t)NE * 2);
    ushort* g1s      = (ushort*)alloc((size_t)NN * HIDIM * 2);
    float*  hr       = (float*) alloc((size_t)NN * HIDIM * 4);
    ushort* g2s      = (ushort*)alloc((size_t)NN * OUTDIM * 2);

    const int nchunks = (NN + 1023) / 1024;  // 49
    const int nb32 = (NN + 31) / 32;         // 1563
    const int nplace = ((NE + PLACE_CHUNK - 1) / PLACE_CHUNK) * NRANGE;

    k_zero<<<(NN + 255) / 256, 256, 0, stream>>>(cnt, NN);
    k_hist<<<(NE + 255) / 256, 256, 0, stream>>>(col, cnt, NE);
    k_dinv<<<(NN + 255) / 256, 256, 0, stream>>>(cnt, dinv, NN);

    k_scan_part<<<nchunks, 1024, 0, stream>>>(cnt, row_ptr, blocksum, NN);
    k_scan_sums<<<1, 64, 0, stream>>>(blocksum, blockoff, row_ptr, nchunks, NN);
    k_scan_add<<<nchunks, 1024, 0, stream>>>(row_ptr, blockoff, NN);
    k_fillinit<<<(NN + 255) / 256, 256, 0, stream>>>(row_ptr, fill, NN);

    k_place<<<nplace, 256, 0, stream>>>(row, col, fill, ssrc, NE);

    k_gemm1<<<(NN + 127) / 128, 256, 0, stream>>>(x, W1, dinv, g1s, NN);
    k_agg1<<<nb32 * 4, 256, 0, stream>>>(g1s, dinv, row_ptr, ssrc, b1, hr);
    k_gemm2<<<(NN + 255) / 256, 256, 0, stream>>>(hr, W2, dinv, g2s, NN);
    k_agg2<<<nb32 * 2, 256, 0, stream>>>(g2s, dinv, row_ptr, ssrc, b2, out);
}

// Round 6
// 369.857 us; speedup vs baseline: 1.7419x; 1.2340x over previous
//
#include <hip/hip_runtime.h>

#define NN 50000
#define NE 1600000
#define INDIM 256
#define HIDIM 128
#define OUTDIM 64

#define NRANGE 8
#define RSPAN 6250            // NN / NRANGE
#define PLACE_EPT 16
#define PLACE_CHUNK (256 * PLACE_EPT)

typedef unsigned int uint;
typedef unsigned short ushort;
typedef __attribute__((ext_vector_type(8))) short bf16x8;
typedef __attribute__((ext_vector_type(4))) float f32x4;

__device__ __forceinline__ ushort f2bf(float f) {
    uint u = __float_as_uint(f);
    uint r = (u + 0x7FFFu + ((u >> 16) & 1u)) >> 16;   // RTNE
    return (ushort)r;
}
__device__ __forceinline__ uint pk2(float a, float b) {
    return (uint)f2bf(a) | ((uint)f2bf(b) << 16);
}
__device__ __forceinline__ float bf_lo(uint u) { return __uint_as_float(u << 16); }
__device__ __forceinline__ float bf_hi(uint u) { return __uint_as_float(u & 0xFFFF0000u); }

// ---------------- init / degree ----------------

__global__ void k_zero(int* __restrict__ cnt, int n) {
    int i = blockIdx.x * 256 + threadIdx.x;
    if (i < n) cnt[i] = 0;
}

__global__ void k_hist(const int* __restrict__ col, int* __restrict__ cnt, int e) {
    int i = blockIdx.x * 256 + threadIdx.x;
    if (i < e) atomicAdd(&cnt[col[i]], 1);
}

__global__ void k_dinv(const int* __restrict__ cnt, float* __restrict__ dinv, int n) {
    int i = blockIdx.x * 256 + threadIdx.x;
    if (i < n) dinv[i] = rsqrtf((float)(cnt[i] + 1));   // +1 self loop
}

// ---------------- weight transpose + bf16 convert ----------------

__global__ void k_w1t(const float* __restrict__ W1, ushort* __restrict__ W1T) {
    int idx = blockIdx.x * 256 + threadIdx.x;     // 32768
    if (idx < INDIM * HIDIM) {
        int k = idx / HIDIM, nn = idx % HIDIM;
        W1T[nn * INDIM + k] = f2bf(W1[idx]);
    }
}

__global__ void k_w2t(const float* __restrict__ W2, ushort* __restrict__ W2T) {
    int idx = blockIdx.x * 256 + threadIdx.x;     // 8192
    if (idx < HIDIM * OUTDIM) {
        int k = idx / OUTDIM, nn = idx % OUTDIM;
        W2T[nn * HIDIM + k] = f2bf(W2[idx]);
    }
}

// ---------------- exclusive scan (3 kernels) ----------------

__global__ void k_scan_part(const int* __restrict__ cnt, int* __restrict__ row_ptr,
                            int* __restrict__ blocksum, int n) {
    __shared__ int wsum[16];
    __shared__ int woff[16];
    int tid = threadIdx.x, lane = tid & 63, wid = tid >> 6;
    int i = blockIdx.x * 1024 + tid;
    int v = (i < n) ? cnt[i] : 0;
    int incl = v;
#pragma unroll
    for (int off = 1; off < 64; off <<= 1) {
        int t = __shfl_up(incl, off);
        if (lane >= off) incl += t;
    }
    if (lane == 63) wsum[wid] = incl;
    __syncthreads();
    if (wid == 0 && lane < 16) {
        int wv = wsum[lane];
        int wincl = wv;
#pragma unroll
        for (int off = 1; off < 16; off <<= 1) {
            int t = __shfl_up(wincl, off);
            if (lane >= off) wincl += t;
        }
        woff[lane] = wincl - wv;
    }
    __syncthreads();
    int excl = incl - v + woff[wid];
    if (i < n) row_ptr[i] = excl;
    if (tid == 1023) blocksum[blockIdx.x] = excl + v;
}

__global__ void k_scan_sums(const int* __restrict__ blocksum, int* __restrict__ blockoff,
                            int* __restrict__ row_ptr, int nchunks, int n) {
    int lane = threadIdx.x;
    int v = (lane < nchunks) ? blocksum[lane] : 0;
    int incl = v;
#pragma unroll
    for (int off = 1; off < 64; off <<= 1) {
        int t = __shfl_up(incl, off);
        if (lane >= off) incl += t;
    }
    blockoff[lane] = incl - v;
    if (lane == nchunks - 1) row_ptr[n] = incl;
}

__global__ void k_scan_add(int* __restrict__ row_ptr, const int* __restrict__ blockoff, int n) {
    int i = blockIdx.x * 1024 + threadIdx.x;
    if (i < n) row_ptr[i] += blockoff[blockIdx.x];
}

__global__ void k_fillinit(const int* __restrict__ row_ptr, int* __restrict__ fill, int n) {
    int i = blockIdx.x * 256 + threadIdx.x;
    if (i < n) fill[i] = row_ptr[i];
}

// ---------------- CSR placement: XCD-local dst-range filtered scatter ----------------

__global__ void k_place(const int* __restrict__ row, const int* __restrict__ col,
                        int* __restrict__ fill, ushort* __restrict__ ssrc, int e) {
    int r = blockIdx.x & (NRANGE - 1);
    int chunk = blockIdx.x >> 3;
    int base = chunk * PLACE_CHUNK + threadIdx.x;
    int lo = r * RSPAN, hi = lo + RSPAN;
#pragma unroll
    for (int k = 0; k < PLACE_EPT; k++) {
        int i = base + k * 256;
        if (i < e) {
            int d = col[i];
            if (d >= lo && d < hi) {
                int pos = atomicAdd(&fill[d], 1);
                ssrc[pos] = (ushort)row[i];
            }
        }
    }
}

// ---------------- GEMM1 (MFMA bf16): x[n][256] @ W1 -> g1s [4][NN][32] bf16 ----------
// Tile 64(M) x 128(N), 4 waves, wave strip = 32 cols (2 n-tiles), 4 m-tiles.
// LDS rows padded to 40 ushorts (80 B) -> frag b128 reads hit 8 distinct bank-quads.

__global__ void k_gemm1(const float* __restrict__ A, const ushort* __restrict__ W1T,
                        const float* __restrict__ dinv, ushort* __restrict__ g1s, int n) {
    __shared__ ushort As[64 * 40];
    __shared__ ushort Bs[128 * 40];
    int tid = threadIdx.x;
    int w = tid >> 6, lane = tid & 63;
    int ln = lane & 15, quad = lane >> 4;
    int row0 = blockIdx.x * 64;
    int n0 = w * 32;

    f32x4 acc[4][2];
#pragma unroll
    for (int m = 0; m < 4; m++)
#pragma unroll
        for (int t = 0; t < 2; t++) acc[m][t] = (f32x4){0.f, 0.f, 0.f, 0.f};

    int ar = tid >> 2;              // A stage: row 0..63
    int ac = (tid & 3) * 8;         // k-chunk 0,8,16,24

    for (int k0 = 0; k0 < INDIM; k0 += 32) {
        {   // stage A: 64 rows x 32 k, f32 -> bf16
            int gr = row0 + ar;
            uint4 u = make_uint4(0, 0, 0, 0);
            if (gr < n) {
                const float* p = A + (size_t)gr * INDIM + k0 + ac;
                float4 v0 = *(const float4*)p;
                float4 v1 = *(const float4*)(p + 4);
                u.x = pk2(v0.x, v0.y); u.y = pk2(v0.z, v0.w);
                u.z = pk2(v1.x, v1.y); u.w = pk2(v1.z, v1.w);
            }
            *(uint4*)(As + ar * 40 + ac) = u;
        }
#pragma unroll
        for (int it = 0; it < 2; it++) {   // stage B: 128 rows x 32 k (bf16 direct)
            int idx = tid + it * 256;
            int bn = idx >> 2, bc = (idx & 3) * 8;
            uint4 u = *(const uint4*)(W1T + (size_t)bn * INDIM + k0 + bc);
            *(uint4*)(Bs + bn * 40 + bc) = u;
        }
        __syncthreads();

        bf16x8 af[4], bf[2];
#pragma unroll
        for (int m = 0; m < 4; m++)
            af[m] = *(const bf16x8*)(As + (m * 16 + ln) * 40 + quad * 8);
#pragma unroll
        for (int t = 0; t < 2; t++)
            bf[t] = *(const bf16x8*)(Bs + (n0 + t * 16 + ln) * 40 + quad * 8);
#pragma unroll
        for (int m = 0; m < 4; m++)
#pragma unroll
            for (int t = 0; t < 2; t++)
                acc[m][t] = __builtin_amdgcn_mfma_f32_16x16x32_bf16(af[m], bf[t], acc[m][t], 0, 0, 0);
        __syncthreads();
    }

#pragma unroll
    for (int m = 0; m < 4; m++) {
#pragma unroll
        for (int r = 0; r < 4; r++) {
            int gr = row0 + m * 16 + quad * 4 + r;
            if (gr < n) {
                float dv = dinv[gr];
#pragma unroll
                for (int t = 0; t < 2; t++) {
                    int cj = t * 16 + ln;   // col within wave's 32-feat slice (slice == w)
                    g1s[((size_t)w * NN + gr) * 32 + cj] = f2bf(acc[m][t][r] * dv);
                }
            }
        }
    }
}

// ---------------- agg1: hrb[s][d][32] = bf16(relu(dinv[d]*(sum g1[src]+g1[d]) + b1)) -

__global__ void k_agg1(const ushort* __restrict__ g1s, const float* __restrict__ dinv,
                       const int* __restrict__ row_ptr, const ushort* __restrict__ ssrc,
                       const float* __restrict__ b1, ushort* __restrict__ hrb) {
    int slice = blockIdx.x & 3;
    int dbase = (blockIdx.x >> 2) * 32;
    int wid = threadIdx.x >> 6, lane = threadIdx.x & 63;
    int grp = lane >> 3, fl = lane & 7;
    int d = dbase + wid * 8 + grp;
    if (d >= NN) return;
    const ushort* gs = g1s + (size_t)slice * NN * 32 + fl * 4;
    float a0 = 0.f, a1 = 0.f, a2 = 0.f, a3 = 0.f;
    int e0 = row_ptr[d], e1 = row_ptr[d + 1];
    int e = e0;
    for (; e + 1 < e1; e += 2) {
        int s0 = ssrc[e], s1 = ssrc[e + 1];
        uint2 u = *(const uint2*)(gs + (size_t)s0 * 32);
        uint2 v = *(const uint2*)(gs + (size_t)s1 * 32);
        a0 += bf_lo(u.x); a1 += bf_hi(u.x); a2 += bf_lo(u.y); a3 += bf_hi(u.y);
        a0 += bf_lo(v.x); a1 += bf_hi(v.x); a2 += bf_lo(v.y); a3 += bf_hi(v.y);
    }
    if (e < e1) {
        int s0 = ssrc[e];
        uint2 u = *(const uint2*)(gs + (size_t)s0 * 32);
        a0 += bf_lo(u.x); a1 += bf_hi(u.x); a2 += bf_lo(u.y); a3 += bf_hi(u.y);
    }
    uint2 ud = *(const uint2*)(gs + (size_t)d * 32);
    a0 += bf_lo(ud.x); a1 += bf_hi(ud.x); a2 += bf_lo(ud.y); a3 += bf_hi(ud.y);
    float dv = dinv[d];
    float4 bb = *(const float4*)(b1 + slice * 32 + fl * 4);
    ushort4 o;
    o.x = f2bf(fmaxf(a0 * dv + bb.x, 0.f));
    o.y = f2bf(fmaxf(a1 * dv + bb.y, 0.f));
    o.z = f2bf(fmaxf(a2 * dv + bb.z, 0.f));
    o.w = f2bf(fmaxf(a3 * dv + bb.w, 0.f));
    *(ushort4*)(hrb + ((size_t)slice * NN + d) * 32 + fl * 4) = o;
}

// ---------------- GEMM2 (MFMA bf16): hrb [4][NN][32] @ W2 -> g2s [2][NN][32] bf16 ----
// Tile 64(M) x 64(N), 4 waves, wave strip = 16 cols (1 n-tile), 4 m-tiles, K=128.

__global__ void k_gemm2(const ushort* __restrict__ hrb, const ushort* __restrict__ W2T,
                        const float* __restrict__ dinv, ushort* __restrict__ g2s, int n) {
    __shared__ ushort As[64 * 40];
    __shared__ ushort Bs[64 * 40];
    int tid = threadIdx.x;
    int w = tid >> 6, lane = tid & 63;
    int ln = lane & 15, quad = lane >> 4;
    int row0 = blockIdx.x * 64;
    int n0 = w * 16;

    f32x4 acc[4];
#pragma unroll
    for (int m = 0; m < 4; m++) acc[m] = (f32x4){0.f, 0.f, 0.f, 0.f};

    int ar = tid >> 2;
    int ac = (tid & 3) * 8;

    for (int k0 = 0; k0 < HIDIM; k0 += 32) {
        int hs = k0 >> 5;               // hr slice == k-chunk
        {   // stage A: 64 rows x 32 k (bf16 direct from sliced hrb)
            int gr = row0 + ar;
            uint4 u = make_uint4(0, 0, 0, 0);
            if (gr < n) u = *(const uint4*)(hrb + ((size_t)hs * NN + gr) * 32 + ac);
            *(uint4*)(As + ar * 40 + ac) = u;
        }
        {   // stage B: 64 rows x 32 k
            int bn = tid >> 2, bc = (tid & 3) * 8;
            uint4 u = *(const uint4*)(W2T + (size_t)bn * HIDIM + k0 + bc);
            *(uint4*)(Bs + bn * 40 + bc) = u;
        }
        __syncthreads();

        bf16x8 bf = *(const bf16x8*)(Bs + (n0 + ln) * 40 + quad * 8);
#pragma unroll
        for (int m = 0; m < 4; m++) {
            bf16x8 af = *(const bf16x8*)(As + (m * 16 + ln) * 40 + quad * 8);
            acc[m] = __builtin_amdgcn_mfma_f32_16x16x32_bf16(af, bf, acc[m], 0, 0, 0);
        }
        __syncthreads();
    }

    int col = n0 + ln;                  // 0..63
    int s2 = col >> 5, cj = col & 31;
#pragma unroll
    for (int m = 0; m < 4; m++) {
#pragma unroll
        for (int r = 0; r < 4; r++) {
            int gr = row0 + m * 16 + quad * 4 + r;
            if (gr < n) {
                g2s[((size_t)s2 * NN + gr) * 32 + cj] = f2bf(acc[m][r] * dinv[gr]);
            }
        }
    }
}

// ---------------- agg2: out[d][64] = dinv[d]*(sum g2[src] + g2[d]) + b2 --------------

__global__ void k_agg2(const ushort* __restrict__ g2s, const float* __restrict__ dinv,
                       const int* __restrict__ row_ptr, const ushort* __restrict__ ssrc,
                       const float* __restrict__ b2, float* __restrict__ out) {
    int slice = blockIdx.x & 1;
    int dbase = (blockIdx.x >> 1) * 32;
    int wid = threadIdx.x >> 6, lane = threadIdx.x & 63;
    int grp = lane >> 3, fl = lane & 7;
    int d = dbase + wid * 8 + grp;
    if (d >= NN) return;
    const ushort* gs = g2s + (size_t)slice * NN * 32 + fl * 4;
    float a0 = 0.f, a1 = 0.f, a2 = 0.f, a3 = 0.f;
    int e0 = row_ptr[d], e1 = row_ptr[d + 1];
    int e = e0;
    for (; e + 1 < e1; e += 2) {
        int s0 = ssrc[e], s1 = ssrc[e + 1];
        uint2 u = *(const uint2*)(gs + (size_t)s0 * 32);
        uint2 v = *(const uint2*)(gs + (size_t)s1 * 32);
        a0 += bf_lo(u.x); a1 += bf_hi(u.x); a2 += bf_lo(u.y); a3 += bf_hi(u.y);
        a0 += bf_lo(v.x); a1 += bf_hi(v.x); a2 += bf_lo(v.y); a3 += bf_hi(v.y);
    }
    if (e < e1) {
        int s0 = ssrc[e];
        uint2 u = *(const uint2*)(gs + (size_t)s0 * 32);
        a0 += bf_lo(u.x); a1 += bf_hi(u.x); a2 += bf_lo(u.y); a3 += bf_hi(u.y);
    }
    uint2 ud = *(const uint2*)(gs + (size_t)d * 32);
    a0 += bf_lo(ud.x); a1 += bf_hi(ud.x); a2 += bf_lo(ud.y); a3 += bf_hi(ud.y);
    float dv = dinv[d];
    float4 bb = *(const float4*)(b2 + slice * 32 + fl * 4);
    float4 r;
    r.x = a0 * dv + bb.x;
    r.y = a1 * dv + bb.y;
    r.z = a2 * dv + bb.z;
    r.w = a3 * dv + bb.w;
    *(float4*)(out + (size_t)d * OUTDIM + slice * 32 + fl * 4) = r;
}

// ---------------- launch ----------------

extern "C" void kernel_launch(void* const* d_in, const int* in_sizes, int n_in,
                              void* d_out, int out_size, void* d_ws, size_t ws_size,
                              hipStream_t stream) {
    const float* x   = (const float*)d_in[0];
    const int*   ei  = (const int*)d_in[1];
    const float* W1  = (const float*)d_in[2];
    const float* b1  = (const float*)d_in[3];
    const float* W2  = (const float*)d_in[4];
    const float* b2  = (const float*)d_in[5];
    float* out = (float*)d_out;

    const int* row = ei;        // sources
    const int* col = ei + NE;   // destinations

    size_t off = 0;
    auto alloc = [&](size_t bytes) {
        void* p = (char*)d_ws + off;
        off += (bytes + 255) & ~(size_t)255;
        return p;
    };
    float*  dinv     = (float*) alloc((size_t)NN * 4);
    int*    cnt      = (int*)   alloc((size_t)NN * 4);
    int*    fill     = (int*)   alloc((size_t)NN * 4);
    int*    row_ptr  = (int*)   alloc((size_t)(NN + 1) * 4);
    int*    blocksum = (int*)   alloc(64 * 4);
    int*    blockoff = (int*)   alloc(64 * 4);
    ushort* ssrc     = (ushort*)alloc((size_t)NE * 2);
    ushort* W1T      = (ushort*)alloc((size_t)INDIM * HIDIM * 2);
    ushort* W2T      = (ushort*)alloc((size_t)HIDIM * OUTDIM * 2);
    ushort* g1s      = (ushort*)alloc((size_t)NN * HIDIM * 2);
    ushort* hrb      = (ushort*)alloc((size_t)NN * HIDIM * 2);
    ushort* g2s      = (ushort*)alloc((size_t)NN * OUTDIM * 2);

    const int nchunks = (NN + 1023) / 1024;  // 49
    const int nb32 = (NN + 31) / 32;         // 1563
    const int nb64 = (NN + 63) / 64;         // 782
    const int nplace = ((NE + PLACE_CHUNK - 1) / PLACE_CHUNK) * NRANGE;

    k_zero<<<(NN + 255) / 256, 256, 0, stream>>>(cnt, NN);
    k_hist<<<(NE + 255) / 256, 256, 0, stream>>>(col, cnt, NE);
    k_dinv<<<(NN + 255) / 256, 256, 0, stream>>>(cnt, dinv, NN);
    k_w1t<<<(INDIM * HIDIM + 255) / 256, 256, 0, stream>>>(W1, W1T);
    k_w2t<<<(HIDIM * OUTDIM + 255) / 256, 256, 0, stream>>>(W2, W2T);

    k_scan_part<<<nchunks, 1024, 0, stream>>>(cnt, row_ptr, blocksum, NN);
    k_scan_sums<<<1, 64, 0, stream>>>(blocksum, blockoff, row_ptr, nchunks, NN);
    k_scan_add<<<nchunks, 1024, 0, stream>>>(row_ptr, blockoff, NN);
    k_fillinit<<<(NN + 255) / 256, 256, 0, stream>>>(row_ptr, fill, NN);

    k_place<<<nplace, 256, 0, stream>>>(row, col, fill, ssrc, NE);

    k_gemm1<<<nb64, 256, 0, stream>>>(x, W1T, dinv, g1s, NN);
    k_agg1<<<nb32 * 4, 256, 0, stream>>>(g1s, dinv, row_ptr, ssrc, b1, hrb);
    k_gemm2<<<nb64, 256, 0, stream>>>(hrb, W2T, dinv, g2s, NN);
    k_agg2<<<nb32 * 2, 256, 0, stream>>>(g2s, dinv, row_ptr, ssrc, b2, out);
}

// Round 7
// 367.491 us; speedup vs baseline: 1.7531x; 1.0064x over previous
//
#include <hip/hip_runtime.h>

#define NN 50000
#define NE 1600000
#define INDIM 256
#define HIDIM 128
#define OUTDIM 64

#define NRANGE 8
#define RSPAN 6250            // NN / NRANGE
#define ACAP 262144           // per-range staging capacity (uint records)
#define AEPT 16
#define ACHUNK (256 * AEPT)   // 4096 edges per bucket block
#define PBLK 125              // place2 blocks per range

typedef unsigned int uint;
typedef unsigned short ushort;
typedef __attribute__((ext_vector_type(8))) short bf16x8;
typedef __attribute__((ext_vector_type(4))) float f32x4;

__device__ __forceinline__ ushort f2bf(float f) {
    uint u = __float_as_uint(f);
    uint r = (u + 0x7FFFu + ((u >> 16) & 1u)) >> 16;   // RTNE
    return (ushort)r;
}
__device__ __forceinline__ uint pk2(float a, float b) {
    return (uint)f2bf(a) | ((uint)f2bf(b) << 16);
}
__device__ __forceinline__ float bf_lo(uint u) { return __uint_as_float(u << 16); }
__device__ __forceinline__ float bf_hi(uint u) { return __uint_as_float(u & 0xFFFF0000u); }

// ---------------- init ----------------

__global__ void k_zero(int* __restrict__ cnt, int* __restrict__ rcur, int n) {
    int i = blockIdx.x * 256 + threadIdx.x;
    if (i < n) cnt[i] = 0;
    if (i < NRANGE) rcur[i] = 0;
}

__global__ void k_dinv(const int* __restrict__ cnt, float* __restrict__ dinv, int n) {
    int i = blockIdx.x * 256 + threadIdx.x;
    if (i < n) dinv[i] = rsqrtf((float)(cnt[i] + 1));   // +1 self loop
}

// ---------------- weight transpose + bf16 convert ----------------

__global__ void k_w1t(const float* __restrict__ W1, ushort* __restrict__ W1T) {
    int idx = blockIdx.x * 256 + threadIdx.x;     // 32768
    if (idx < INDIM * HIDIM) {
        int k = idx / HIDIM, nn = idx % HIDIM;
        W1T[nn * INDIM + k] = f2bf(W1[idx]);
    }
}

__global__ void k_w2t(const float* __restrict__ W2, ushort* __restrict__ W2T) {
    int idx = blockIdx.x * 256 + threadIdx.x;     // 8192
    if (idx < HIDIM * OUTDIM) {
        int k = idx / OUTDIM, nn = idx % OUTDIM;
        W2T[nn * HIDIM + k] = f2bf(W2[idx]);
    }
}

// ---------------- phase A: bucket edges by dst-range + fused degree histogram -------

__global__ void k_bucket(const int* __restrict__ row, const int* __restrict__ col,
                         int* __restrict__ cnt, int* __restrict__ rcur,
                         uint* __restrict__ staged) {
    __shared__ int bcnt[NRANGE];
    __shared__ int bbase[NRANGE];
    __shared__ int bcur[NRANGE];
    int tid = threadIdx.x;
    if (tid < NRANGE) bcnt[tid] = 0;
    __syncthreads();
    int base = blockIdx.x * ACHUNK + tid;
    int sv[AEPT], dv[AEPT];
#pragma unroll
    for (int k = 0; k < AEPT; k++) {
        int i = base + k * 256;
        if (i < NE) {
            dv[k] = col[i];
            sv[k] = row[i];
            atomicAdd(&cnt[dv[k]], 1);           // degree histogram (fused)
            atomicAdd(&bcnt[dv[k] / RSPAN], 1);  // LDS range count
        } else {
            dv[k] = -1;
        }
    }
    __syncthreads();
    if (tid < NRANGE) {
        bbase[tid] = atomicAdd(&rcur[tid], bcnt[tid]);
        bcur[tid] = 0;
    }
    __syncthreads();
#pragma unroll
    for (int k = 0; k < AEPT; k++) {
        if (dv[k] >= 0) {
            int r = dv[k] / RSPAN;
            int off = atomicAdd(&bcur[r], 1);
            staged[(size_t)r * ACAP + bbase[r] + off] =
                ((uint)sv[k] << 13) | (uint)(dv[k] - r * RSPAN);
        }
    }
}

// ---------------- exclusive scan (3 kernels) ----------------

__global__ void k_scan_part(const int* __restrict__ cnt, int* __restrict__ row_ptr,
                            int* __restrict__ blocksum, int n) {
    __shared__ int wsum[16];
    __shared__ int woff[16];
    int tid = threadIdx.x, lane = tid & 63, wid = tid >> 6;
    int i = blockIdx.x * 1024 + tid;
    int v = (i < n) ? cnt[i] : 0;
    int incl = v;
#pragma unroll
    for (int off = 1; off < 64; off <<= 1) {
        int t = __shfl_up(incl, off);
        if (lane >= off) incl += t;
    }
    if (lane == 63) wsum[wid] = incl;
    __syncthreads();
    if (wid == 0 && lane < 16) {
        int wv = wsum[lane];
        int wincl = wv;
#pragma unroll
        for (int off = 1; off < 16; off <<= 1) {
            int t = __shfl_up(wincl, off);
            if (lane >= off) wincl += t;
        }
        woff[lane] = wincl - wv;
    }
    __syncthreads();
    int excl = incl - v + woff[wid];
    if (i < n) row_ptr[i] = excl;
    if (tid == 1023) blocksum[blockIdx.x] = excl + v;
}

__global__ void k_scan_sums(const int* __restrict__ blocksum, int* __restrict__ blockoff,
                            int* __restrict__ row_ptr, int nchunks, int n) {
    int lane = threadIdx.x;
    int v = (lane < nchunks) ? blocksum[lane] : 0;
    int incl = v;
#pragma unroll
    for (int off = 1; off < 64; off <<= 1) {
        int t = __shfl_up(incl, off);
        if (lane >= off) incl += t;
    }
    blockoff[lane] = incl - v;
    if (lane == nchunks - 1) row_ptr[n] = incl;
}

__global__ void k_scan_add(int* __restrict__ row_ptr, int* __restrict__ fill,
                           const int* __restrict__ blockoff, int n) {
    int i = blockIdx.x * 1024 + threadIdx.x;
    if (i < n) {
        int v = row_ptr[i] + blockoff[blockIdx.x];
        row_ptr[i] = v;
        fill[i] = v;        // fused fill-cursor init
    }
}

// ---------------- phase B: XCD-local CSR placement from staged records ---------------

__global__ void k_place2(const uint* __restrict__ staged, const int* __restrict__ rcur,
                         int* __restrict__ fill, ushort* __restrict__ ssrc) {
    int r = blockIdx.x & (NRANGE - 1);
    int sb = blockIdx.x >> 3;
    int count = rcur[r];
    const uint* st = staged + (size_t)r * ACAP;
    int lo = r * RSPAN;
    for (int i = sb * 256 + threadIdx.x; i < count; i += PBLK * 256) {
        uint rec = st[i];
        int d = lo + (int)(rec & 8191u);
        int pos = atomicAdd(&fill[d], 1);
        ssrc[pos] = (ushort)(rec >> 13);
    }
}

// ---------------- GEMM1 (MFMA bf16): x[n][256] @ W1 -> g1s [4][NN][32] bf16 ----------

__global__ void k_gemm1(const float* __restrict__ A, const ushort* __restrict__ W1T,
                        const float* __restrict__ dinv, ushort* __restrict__ g1s, int n) {
    __shared__ ushort As[64 * 40];
    __shared__ ushort Bs[128 * 40];
    int tid = threadIdx.x;
    int w = tid >> 6, lane = tid & 63;
    int ln = lane & 15, quad = lane >> 4;
    int row0 = blockIdx.x * 64;
    int n0 = w * 32;

    f32x4 acc[4][2];
#pragma unroll
    for (int m = 0; m < 4; m++)
#pragma unroll
        for (int t = 0; t < 2; t++) acc[m][t] = (f32x4){0.f, 0.f, 0.f, 0.f};

    int ar = tid >> 2;
    int ac = (tid & 3) * 8;

    for (int k0 = 0; k0 < INDIM; k0 += 32) {
        {   // stage A: 64 rows x 32 k, f32 -> bf16
            int gr = row0 + ar;
            uint4 u = make_uint4(0, 0, 0, 0);
            if (gr < n) {
                const float* p = A + (size_t)gr * INDIM + k0 + ac;
                float4 v0 = *(const float4*)p;
                float4 v1 = *(const float4*)(p + 4);
                u.x = pk2(v0.x, v0.y); u.y = pk2(v0.z, v0.w);
                u.z = pk2(v1.x, v1.y); u.w = pk2(v1.z, v1.w);
            }
            *(uint4*)(As + ar * 40 + ac) = u;
        }
#pragma unroll
        for (int it = 0; it < 2; it++) {   // stage B: 128 rows x 32 k
            int idx = tid + it * 256;
            int bn = idx >> 2, bc = (idx & 3) * 8;
            uint4 u = *(const uint4*)(W1T + (size_t)bn * INDIM + k0 + bc);
            *(uint4*)(Bs + bn * 40 + bc) = u;
        }
        __syncthreads();

        bf16x8 af[4], bf[2];
#pragma unroll
        for (int m = 0; m < 4; m++)
            af[m] = *(const bf16x8*)(As + (m * 16 + ln) * 40 + quad * 8);
#pragma unroll
        for (int t = 0; t < 2; t++)
            bf[t] = *(const bf16x8*)(Bs + (n0 + t * 16 + ln) * 40 + quad * 8);
#pragma unroll
        for (int m = 0; m < 4; m++)
#pragma unroll
            for (int t = 0; t < 2; t++)
                acc[m][t] = __builtin_amdgcn_mfma_f32_16x16x32_bf16(af[m], bf[t], acc[m][t], 0, 0, 0);
        __syncthreads();
    }

#pragma unroll
    for (int m = 0; m < 4; m++) {
#pragma unroll
        for (int r = 0; r < 4; r++) {
            int gr = row0 + m * 16 + quad * 4 + r;
            if (gr < n) {
                float dv = dinv[gr];
#pragma unroll
                for (int t = 0; t < 2; t++) {
                    int cj = t * 16 + ln;
                    g1s[((size_t)w * NN + gr) * 32 + cj] = f2bf(acc[m][t][r] * dv);
                }
            }
        }
    }
}

// ---------------- agg1: hrb[s][d][32] = bf16(relu(dinv[d]*(sum g1[src]+g1[d]) + b1)) -

__global__ void k_agg1(const ushort* __restrict__ g1s, const float* __restrict__ dinv,
                       const int* __restrict__ row_ptr, const ushort* __restrict__ ssrc,
                       const float* __restrict__ b1, ushort* __restrict__ hrb) {
    int slice = blockIdx.x & 3;
    int dbase = (blockIdx.x >> 2) * 32;
    int wid = threadIdx.x >> 6, lane = threadIdx.x & 63;
    int grp = lane >> 3, fl = lane & 7;
    int d = dbase + wid * 8 + grp;
    if (d >= NN) return;
    const ushort* gs = g1s + (size_t)slice * NN * 32 + fl * 4;
    float a0 = 0.f, a1 = 0.f, a2 = 0.f, a3 = 0.f;
    int e0 = row_ptr[d], e1 = row_ptr[d + 1];
    int e = e0;
    for (; e + 1 < e1; e += 2) {
        int s0 = ssrc[e], s1 = ssrc[e + 1];
        uint2 u = *(const uint2*)(gs + (size_t)s0 * 32);
        uint2 v = *(const uint2*)(gs + (size_t)s1 * 32);
        a0 += bf_lo(u.x); a1 += bf_hi(u.x); a2 += bf_lo(u.y); a3 += bf_hi(u.y);
        a0 += bf_lo(v.x); a1 += bf_hi(v.x); a2 += bf_lo(v.y); a3 += bf_hi(v.y);
    }
    if (e < e1) {
        int s0 = ssrc[e];
        uint2 u = *(const uint2*)(gs + (size_t)s0 * 32);
        a0 += bf_lo(u.x); a1 += bf_hi(u.x); a2 += bf_lo(u.y); a3 += bf_hi(u.y);
    }
    uint2 ud = *(const uint2*)(gs + (size_t)d * 32);
    a0 += bf_lo(ud.x); a1 += bf_hi(ud.x); a2 += bf_lo(ud.y); a3 += bf_hi(ud.y);
    float dv = dinv[d];
    float4 bb = *(const float4*)(b1 + slice * 32 + fl * 4);
    ushort4 o;
    o.x = f2bf(fmaxf(a0 * dv + bb.x, 0.f));
    o.y = f2bf(fmaxf(a1 * dv + bb.y, 0.f));
    o.z = f2bf(fmaxf(a2 * dv + bb.z, 0.f));
    o.w = f2bf(fmaxf(a3 * dv + bb.w, 0.f));
    *(ushort4*)(hrb + ((size_t)slice * NN + d) * 32 + fl * 4) = o;
}

// ---------------- GEMM2 (MFMA bf16): hrb [4][NN][32] @ W2 -> g2s [2][NN][32] bf16 ----

__global__ void k_gemm2(const ushort* __restrict__ hrb, const ushort* __restrict__ W2T,
                        const float* __restrict__ dinv, ushort* __restrict__ g2s, int n) {
    __shared__ ushort As[64 * 40];
    __shared__ ushort Bs[64 * 40];
    int tid = threadIdx.x;
    int w = tid >> 6, lane = tid & 63;
    int ln = lane & 15, quad = lane >> 4;
    int row0 = blockIdx.x * 64;
    int n0 = w * 16;

    f32x4 acc[4];
#pragma unroll
    for (int m = 0; m < 4; m++) acc[m] = (f32x4){0.f, 0.f, 0.f, 0.f};

    int ar = tid >> 2;
    int ac = (tid & 3) * 8;

    for (int k0 = 0; k0 < HIDIM; k0 += 32) {
        int hs = k0 >> 5;
        {   // stage A
            int gr = row0 + ar;
            uint4 u = make_uint4(0, 0, 0, 0);
            if (gr < n) u = *(const uint4*)(hrb + ((size_t)hs * NN + gr) * 32 + ac);
            *(uint4*)(As + ar * 40 + ac) = u;
        }
        {   // stage B
            int bn = tid >> 2, bc = (tid & 3) * 8;
            uint4 u = *(const uint4*)(W2T + (size_t)bn * HIDIM + k0 + bc);
            *(uint4*)(Bs + bn * 40 + bc) = u;
        }
        __syncthreads();

        bf16x8 bf = *(const bf16x8*)(Bs + (n0 + ln) * 40 + quad * 8);
#pragma unroll
        for (int m = 0; m < 4; m++) {
            bf16x8 af = *(const bf16x8*)(As + (m * 16 + ln) * 40 + quad * 8);
            acc[m] = __builtin_amdgcn_mfma_f32_16x16x32_bf16(af, bf, acc[m], 0, 0, 0);
        }
        __syncthreads();
    }

    int col = n0 + ln;
    int s2 = col >> 5, cj = col & 31;
#pragma unroll
    for (int m = 0; m < 4; m++) {
#pragma unroll
        for (int r = 0; r < 4; r++) {
            int gr = row0 + m * 16 + quad * 4 + r;
            if (gr < n) {
                g2s[((size_t)s2 * NN + gr) * 32 + cj] = f2bf(acc[m][r] * dinv[gr]);
            }
        }
    }
}

// ---------------- agg2: out[d][64] = dinv[d]*(sum g2[src] + g2[d]) + b2 --------------

__global__ void k_agg2(const ushort* __restrict__ g2s, const float* __restrict__ dinv,
                       const int* __restrict__ row_ptr, const ushort* __restrict__ ssrc,
                       const float* __restrict__ b2, float* __restrict__ out) {
    int slice = blockIdx.x & 1;
    int dbase = (blockIdx.x >> 1) * 32;
    int wid = threadIdx.x >> 6, lane = threadIdx.x & 63;
    int grp = lane >> 3, fl = lane & 7;
    int d = dbase + wid * 8 + grp;
    if (d >= NN) return;
    const ushort* gs = g2s + (size_t)slice * NN * 32 + fl * 4;
    float a0 = 0.f, a1 = 0.f, a2 = 0.f, a3 = 0.f;
    int e0 = row_ptr[d], e1 = row_ptr[d + 1];
    int e = e0;
    for (; e + 1 < e1; e += 2) {
        int s0 = ssrc[e], s1 = ssrc[e + 1];
        uint2 u = *(const uint2*)(gs + (size_t)s0 * 32);
        uint2 v = *(const uint2*)(gs + (size_t)s1 * 32);
        a0 += bf_lo(u.x); a1 += bf_hi(u.x); a2 += bf_lo(u.y); a3 += bf_hi(u.y);
        a0 += bf_lo(v.x); a1 += bf_hi(v.x); a2 += bf_lo(v.y); a3 += bf_hi(v.y);
    }
    if (e < e1) {
        int s0 = ssrc[e];
        uint2 u = *(const uint2*)(gs + (size_t)s0 * 32);
        a0 += bf_lo(u.x); a1 += bf_hi(u.x); a2 += bf_lo(u.y); a3 += bf_hi(u.y);
    }
    uint2 ud = *(const uint2*)(gs + (size_t)d * 32);
    a0 += bf_lo(ud.x); a1 += bf_hi(ud.x); a2 += bf_lo(ud.y); a3 += bf_hi(ud.y);
    float dv = dinv[d];
    float4 bb = *(const float4*)(b2 + slice * 32 + fl * 4);
    float4 r;
    r.x = a0 * dv + bb.x;
    r.y = a1 * dv + bb.y;
    r.z = a2 * dv + bb.z;
    r.w = a3 * dv + bb.w;
    *(float4*)(out + (size_t)d * OUTDIM + slice * 32 + fl * 4) = r;
}

// ---------------- launch ----------------

extern "C" void kernel_launch(void* const* d_in, const int* in_sizes, int n_in,
                              void* d_out, int out_size, void* d_ws, size_t ws_size,
                              hipStream_t stream) {
    const float* x   = (const float*)d_in[0];
    const int*   ei  = (const int*)d_in[1];
    const float* W1  = (const float*)d_in[2];
    const float* b1  = (const float*)d_in[3];
    const float* W2  = (const float*)d_in[4];
    const float* b2  = (const float*)d_in[5];
    float* out = (float*)d_out;

    const int* row = ei;        // sources
    const int* col = ei + NE;   // destinations

    size_t off = 0;
    auto alloc = [&](size_t bytes) {
        void* p = (char*)d_ws + off;
        off += (bytes + 255) & ~(size_t)255;
        return p;
    };
    float*  dinv     = (float*) alloc((size_t)NN * 4);
    int*    cnt      = (int*)   alloc((size_t)NN * 4);
    int*    fill     = (int*)   alloc((size_t)NN * 4);
    int*    row_ptr  = (int*)   alloc((size_t)(NN + 1) * 4);
    int*    blocksum = (int*)   alloc(64 * 4);
    int*    blockoff = (int*)   alloc(64 * 4);
    int*    rcur     = (int*)   alloc(NRANGE * 4);
    uint*   staged   = (uint*)  alloc((size_t)NRANGE * ACAP * 4);   // 8 MB
    ushort* ssrc     = (ushort*)alloc((size_t)NE * 2);
    ushort* W1T      = (ushort*)alloc((size_t)INDIM * HIDIM * 2);
    ushort* W2T      = (ushort*)alloc((size_t)HIDIM * OUTDIM * 2);
    ushort* g1s      = (ushort*)alloc((size_t)NN * HIDIM * 2);
    ushort* hrb      = (ushort*)alloc((size_t)NN * HIDIM * 2);
    ushort* g2s      = (ushort*)alloc((size_t)NN * OUTDIM * 2);

    const int nchunks = (NN + 1023) / 1024;  // 49
    const int nb32 = (NN + 31) / 32;         // 1563
    const int nb64 = (NN + 63) / 64;         // 782
    const int nbucket = (NE + ACHUNK - 1) / ACHUNK;   // 391

    k_zero<<<(NN + 255) / 256, 256, 0, stream>>>(cnt, rcur, NN);
    k_w1t<<<(INDIM * HIDIM + 255) / 256, 256, 0, stream>>>(W1, W1T);
    k_w2t<<<(HIDIM * OUTDIM + 255) / 256, 256, 0, stream>>>(W2, W2T);

    k_bucket<<<nbucket, 256, 0, stream>>>(row, col, cnt, rcur, staged);

    k_dinv<<<(NN + 255) / 256, 256, 0, stream>>>(cnt, dinv, NN);
    k_scan_part<<<nchunks, 1024, 0, stream>>>(cnt, row_ptr, blocksum, NN);
    k_scan_sums<<<1, 64, 0, stream>>>(blocksum, blockoff, row_ptr, nchunks, NN);
    k_scan_add<<<nchunks, 1024, 0, stream>>>(row_ptr, fill, blockoff, NN);

    k_place2<<<NRANGE * PBLK, 256, 0, stream>>>(staged, rcur, fill, ssrc);

    k_gemm1<<<nb64, 256, 0, stream>>>(x, W1T, dinv, g1s, NN);
    k_agg1<<<nb32 * 4, 256, 0, stream>>>(g1s, dinv, row_ptr, ssrc, b1, hrb);
    k_gemm2<<<nb64, 256, 0, stream>>>(hrb, W2T, dinv, g2s, NN);
    k_agg2<<<nb32 * 2, 256, 0, stream>>>(g2s, dinv, row_ptr, ssrc, b2, out);
}